// Round 11
// baseline (370.410 us; speedup 1.0000x reference)
//
#include <hip/hip_runtime.h>

#define N_SAMP   1024
#define IN_F     512
#define OUT_F    512
#define N_HEADS  32
#define N_SPLITS 4
#define DELTA_SCALE 0.1f

__device__ __forceinline__ void fma4(float4& a, float x, const float4& w) {
    a.x += x * w.x; a.y += x * w.y; a.z += x * w.z; a.w += x * w.w;
}
__device__ __forceinline__ void add4(float4& a, const float4& b) {
    a.x += b.x; a.y += b.y; a.z += b.z; a.w += b.w;
}

// R11: fat 512-thread blocks, one per group-stream.
//  - lane = (c4 = lane&15 -> 4 cols, p = (lane>>4)&3 -> k parity). Per iter a
//    lane loads W[4it+p][c..c+3]; per wave-instr that's 4 rows x 256 B; per
//    BLOCK iter: 4 complete rows = 8 KB linear -> near-contiguous 1 MB stream
//    (R1/R9/R10 all pinned at ~1.3 TB/s effective with narrow strided tiles).
//  - k-split is IN-WAVE: reduce with __shfl_xor 16/32 at the end. No LDS
//    round-trip, no atomics (R3), no block k-split.
//  - depth-8 prefetch ring wreg[8], indices are unroll-constants (R8's trap
//    was a runtime-varying buffer index -> scratch). 8 KB/wave in flight.
//  - acc 64 + wreg 32 VGPR => no spill (R10's WRITE_SIZE 18 MB tell).
//  - X transposed in LDS Xs[k][16]; 4x ds_read_b128 per iter (banks 2-way = free).
//  - delta -> raw partials to ws (combine scales); base -> out + bias.
template <bool DELTA, int SSTRIDE>
__device__ __forceinline__ void role512(
    const float* __restrict__ X, const int* __restrict__ head_ix,
    const int* __restrict__ split_ix, const float* __restrict__ Wslice,
    const float* __restrict__ bias_h, float* __restrict__ dst,
    int g, int sampleBase, float* Xs, int* list, int* wsum)
{
    const int tid  = threadIdx.x;
    const int lane = tid & 63, wave = tid >> 6;
    const int c4   = lane & 15;
    const int p    = (lane >> 4) & 3;
    const int cb   = wave * 64 + c4 * 4;     // this lane's 4 output columns

    // deterministic order-preserving compaction (all blocks of g agree)
    int run = 0;
    for (int r = 0; r < N_SAMP / 512; ++r) {
        const int i   = r * 512 + tid;
        const int key = DELTA ? head_ix[i] * N_SPLITS + split_ix[i] : head_ix[i];
        const bool hit = (key == g);
        const unsigned long long m = __ballot(hit);
        if (lane == 0) wsum[wave] = __popcll(m);
        __syncthreads();
        int base = run, tot = 0;
        for (int w = 0; w < 8; ++w) {
            if (w < wave) base += wsum[w];
            tot += wsum[w];
        }
        if (hit)
            list[base + __popcll(m & ((1ULL << lane) - 1ULL))] = i;
        run += tot;
        __syncthreads();
    }
    const int total = run;
    if (total == 0) return;                  // block-uniform

    float4 bv;
    if (!DELTA) bv = *(const float4*)(bias_h + cb);

    const float* wp0 = Wslice + cb;          // + k*OUT_F

    for (int s0 = sampleBase; s0 < total; s0 += SSTRIDE) {
        const int nc = min(total - s0, 16);

        __syncthreads();                     // all waves done with prev Xs
        // stage Xs[k][16] transposed, zero-filled past nc
        for (int i = tid; i < 16 * (IN_F / 4); i += 512) {
            const int s = i >> 7, q = i & 127;
            float4 v = make_float4(0.f, 0.f, 0.f, 0.f);
            if (s < nc)
                v = *(const float4*)(X + (size_t)list[s0 + s] * IN_F + q * 4);
            Xs[(q * 4 + 0) * 16 + s] = v.x;
            Xs[(q * 4 + 1) * 16 + s] = v.y;
            Xs[(q * 4 + 2) * 16 + s] = v.z;
            Xs[(q * 4 + 3) * 16 + s] = v.w;
        }
        __syncthreads();

        float4 acc[16];
#pragma unroll
        for (int j = 0; j < 16; ++j) acc[j] = make_float4(0.f, 0.f, 0.f, 0.f);

        // depth-8 prefetch ring; 128 iterations cover k = 4*it + p
        float4 wreg[8];
#pragma unroll
        for (int u = 0; u < 8; ++u)
            wreg[u] = *(const float4*)(wp0 + (size_t)(4 * u + p) * OUT_F);

        for (int it0 = 0; it0 < 128; it0 += 8) {
#pragma unroll
            for (int u = 0; u < 8; ++u) {    // u is unroll-constant
                const int it = it0 + u;
                const int k  = 4 * it + p;
                const float4 wv = wreg[u];   // waits oldest (vmcnt(7))
                const float* xr = Xs + k * 16;
#pragma unroll
                for (int q = 0; q < 4; ++q) {
                    const float4 xq = *(const float4*)(xr + q * 4);
                    fma4(acc[q * 4 + 0], xq.x, wv);
                    fma4(acc[q * 4 + 1], xq.y, wv);
                    fma4(acc[q * 4 + 2], xq.z, wv);
                    fma4(acc[q * 4 + 3], xq.w, wv);
                }
                int nit = it + 8;            // clamped tail: L1-hit re-load
                if (nit > 127) nit = 127;
                wreg[u] = *(const float4*)(wp0 + (size_t)(4 * nit + p) * OUT_F);
            }
        }

        // in-wave 4-way k-parity reduction (lane bits 4,5)
#pragma unroll
        for (int j = 0; j < 16; ++j) {
            acc[j].x += __shfl_xor(acc[j].x, 16);
            acc[j].y += __shfl_xor(acc[j].y, 16);
            acc[j].z += __shfl_xor(acc[j].z, 16);
            acc[j].w += __shfl_xor(acc[j].w, 16);
            acc[j].x += __shfl_xor(acc[j].x, 32);
            acc[j].y += __shfl_xor(acc[j].y, 32);
            acc[j].z += __shfl_xor(acc[j].z, 32);
            acc[j].w += __shfl_xor(acc[j].w, 32);
        }
        if (p == 0) {                        // lanes 0..15: sole owners
#pragma unroll
            for (int j = 0; j < 16; ++j) {
                if (j < nc) {
                    float* op = dst + (size_t)list[s0 + j] * OUT_F + cb;
                    float4 v = acc[j];
                    if (!DELTA) add4(v, bv);
                    *(float4*)op = v;
                }
            }
        }
    }
}

// 256 blocks x 512 thr, 1/CU, balanced roles:
//  even bid -> delta: one block per combo (streams its whole 1 MB D slice,
//              raw partials to ws)
//  odd  bid -> base: (head, sg 0..3): slots sg*16 + m*64 of the head's list,
//              streams the head's 1 MB W slice, out = acc + bias
__global__ __launch_bounds__(512, 1) void lms_fused(
    const float* __restrict__ X, const int* __restrict__ head_ix,
    const int* __restrict__ split_ix, const float* __restrict__ W,
    const float* __restrict__ D, const float* __restrict__ bias,
    float* __restrict__ out, float* __restrict__ ws)
{
    __shared__ float Xs[IN_F * 16];          // 32 KB
    __shared__ int   list[N_SAMP];
    __shared__ int   wsum[8];

    const int bid = blockIdx.x;
    if ((bid & 1) == 0) {
        const int combo = bid >> 1;          // 0..127
        role512<true, 16>(X, head_ix, split_ix,
            D + (size_t)combo * IN_F * OUT_F, nullptr,
            ws, combo, 0, Xs, list, wsum);
    } else {
        const int id   = bid >> 1;           // 0..127
        const int head = id & 31, sg = id >> 5;
        role512<false, 64>(X, head_ix, split_ix,
            W + (size_t)head * IN_F * OUT_F, bias + (size_t)head * OUT_F,
            out, head, sg * 16, Xs, list, wsum);
    }
}

// out += 0.1 * ws (every ws element written: each sample's combo is nonempty
// by construction; the combo block's 8 waves cover all 512 cols)
__global__ __launch_bounds__(256) void combine_kernel(
    float* __restrict__ out, const float* __restrict__ ws)
{
    const int i = blockIdx.x * 256 + threadIdx.x;
    float4 o = ((float4*)out)[i];
    const float4 d = ((const float4*)ws)[i];
    o.x += DELTA_SCALE * d.x; o.y += DELTA_SCALE * d.y;
    o.z += DELTA_SCALE * d.z; o.w += DELTA_SCALE * d.w;
    ((float4*)out)[i] = o;
}

extern "C" void kernel_launch(void* const* d_in, const int* in_sizes, int n_in,
                              void* d_out, int out_size, void* d_ws, size_t ws_size,
                              hipStream_t stream) {
    const float* X        = (const float*)d_in[0];
    const int*   head_ix  = (const int*)d_in[1];
    const int*   split_ix = (const int*)d_in[2];
    const float* W        = (const float*)d_in[3];
    const float* D        = (const float*)d_in[4];
    const float* bias     = (const float*)d_in[5];
    float*       out      = (float*)d_out;
    float*       ws       = (float*)d_ws;

    lms_fused<<<256, 512, 0, stream>>>(X, head_ix, split_ix, W, D, bias, out, ws);
    combine_kernel<<<(N_SAMP * OUT_F / 4) / 256, 256, 0, stream>>>(out, ws);
}